// Round 10
// baseline (344.812 us; speedup 1.0000x reference)
//
#include <hip/hip_runtime.h>
#include <math.h>

// ---------------------------------------------------------------------------
// DeepSeek MLHA attention. Round 10: 32q-per-wave flash attention with
// global_load_lds DMA staging (pre-swizzled source), 2-wave blocks.
// B=2, T=2048, hidden=2048, NH=16, NKV=4, HD=128, latent=256, kv_dim=512.
// ---------------------------------------------------------------------------

#define AS1 __attribute__((address_space(1)))
#define AS3 __attribute__((address_space(3)))

typedef short bf16x8 __attribute__((ext_vector_type(8)));
typedef float f32x4 __attribute__((ext_vector_type(4)));

__device__ __forceinline__ unsigned short f2bf(float x) {
  union { float f; unsigned int u; } q; q.f = x;
  unsigned int u = q.u;
  u += 0x7FFFu + ((u >> 16) & 1u);   // RNE
  return (unsigned short)(u >> 16);
}
__device__ __forceinline__ float bf2f(unsigned short x) {
  union { unsigned int u; float f; } q; q.u = ((unsigned int)x) << 16;
  return q.f;
}
__device__ __forceinline__ unsigned int pack2bf(float a, float b) {
  return (unsigned int)f2bf(a) | ((unsigned int)f2bf(b) << 16);
}

// Read-side swizzles (short index). DMA source uses the exact inverse.
__device__ __forceinline__ int swzK(int row, int ch) {   // K tile [32][128] bf16
  return (((row << 8) + (ch << 4)) ^ ((row & 7) << 4)) >> 1;
}
__device__ __forceinline__ int swzV(int row, int ch) {   // V^T tile [128][32] bf16
  return (((row << 6) + (ch << 4)) ^ ((row & 7) << 4)) >> 1;
}

// --- RoPE cos/sin table ----------------------------------------------------
__global__ __launch_bounds__(256) void rope_table(float* __restrict__ cost,
                                                  float* __restrict__ sint,
                                                  int T) {
  int idx = blockIdx.x * 256 + threadIdx.x;
  if (idx >= T * 64) return;
  int t = idx >> 6, j = idx & 63;
  double invf = pow(10000.0, -(double)j / 64.0);
  double ang = (double)t * invf;
  cost[idx] = (float)cos(ang);
  sint[idx] = (float)sin(ang);
}

// --- fp32 -> bf16 convert --------------------------------------------------
__global__ __launch_bounds__(256) void conv_bf16(const float* __restrict__ src,
                                                 unsigned short* __restrict__ dst,
                                                 int n) {
  int i = (blockIdx.x * 256 + threadIdx.x) * 4;
  if (i >= n) return;
  float4 f = *(const float4*)(src + i);
  ushort4 o;
  o.x = f2bf(f.x); o.y = f2bf(f.y); o.z = f2bf(f.z); o.w = f2bf(f.w);
  *(ushort4*)(dst + i) = o;
}

// --- bf16 MFMA NT-GEMM (m97 structure, unchanged) --------------------------
template <bool OUT_BF16>
__global__ __launch_bounds__(256) void gemm_mfma(const unsigned short* __restrict__ A,
                                                 const unsigned short* __restrict__ W,
                                                 void* __restrict__ Cv,
                                                 int M, int N, int K) {
  __shared__ unsigned short Asl[128 * 32];
  __shared__ unsigned short Wsl[128 * 32];
  int tid = threadIdx.x;
  int w = tid >> 6, lane = tid & 63;
  int g = lane >> 4, c = lane & 15;
  int wm = w >> 1, wn = w & 1;
  int m0 = blockIdx.y * 128, n0 = blockIdx.x * 128;

  f32x4 acc[4][4] = {};

  for (int k0 = 0; k0 < K; k0 += 32) {
#pragma unroll
    for (int i = 0; i < 2; ++i) {
      int idx = i * 256 + tid;
      int row = idx >> 2;
      int kk = (idx & 3) * 8;
      __builtin_amdgcn_global_load_lds(
          (const AS1 void*)(A + (size_t)(m0 + row) * K + k0 + kk),
          (AS3 void*)(Asl + ((size_t)i * 256 + (w << 6)) * 8), 16, 0, 0);
      __builtin_amdgcn_global_load_lds(
          (const AS1 void*)(W + (size_t)(n0 + row) * K + k0 + kk),
          (AS3 void*)(Wsl + ((size_t)i * 256 + (w << 6)) * 8), 16, 0, 0);
    }
    __syncthreads();
    bf16x8 af[4], wf[4];
#pragma unroll
    for (int mi = 0; mi < 4; ++mi)
      af[mi] = *(const bf16x8*)(Asl + (wm * 64 + mi * 16 + c) * 32 + g * 8);
#pragma unroll
    for (int ni = 0; ni < 4; ++ni)
      wf[ni] = *(const bf16x8*)(Wsl + (wn * 64 + ni * 16 + c) * 32 + g * 8);
#pragma unroll
    for (int mi = 0; mi < 4; ++mi)
#pragma unroll
      for (int ni = 0; ni < 4; ++ni)
        acc[mi][ni] = __builtin_amdgcn_mfma_f32_16x16x32_bf16(af[mi], wf[ni],
                                                              acc[mi][ni], 0, 0, 0);
    __syncthreads();
  }
#pragma unroll
  for (int mi = 0; mi < 4; ++mi)
#pragma unroll
    for (int r = 0; r < 4; ++r) {
      size_t mrow = (size_t)(m0 + wm * 64 + mi * 16 + g * 4 + r) * N;
#pragma unroll
      for (int ni = 0; ni < 4; ++ni) {
        int n = n0 + wn * 64 + ni * 16 + c;
        if (OUT_BF16)
          ((unsigned short*)Cv)[mrow + n] = f2bf(acc[mi][ni][r]);
        else
          ((float*)Cv)[mrow + n] = acc[mi][ni][r];
      }
    }
}

// --- in-place RoPE on bf16 buffer ------------------------------------------
__global__ __launch_bounds__(256) void rope_ip_bf16(unsigned short* __restrict__ buf,
                                                    int nheads, int T,
                                                    const float* __restrict__ cost,
                                                    const float* __restrict__ sint,
                                                    float scale) {
  int idx = blockIdx.x * 256 + threadIdx.x;
  int d = idx & 63;
  int rest = idx >> 6;
  int h = rest % nheads;
  int bt = rest / nheads;
  int t = bt & (T - 1);
  unsigned short* p = buf + (size_t)bt * nheads * 128 + h * 128;
  float cc = cost[t * 64 + d], ss = sint[t * 64 + d];
  float x0 = bf2f(p[d]), x1 = bf2f(p[d + 64]);
  p[d]      = f2bf((x0 * cc - x1 * ss) * scale);
  p[d + 64] = f2bf((x1 * cc + x0 * ss) * scale);
}

// --- V transpose -> vtb [b][kvh][128 d][2048 t] ----------------------------
__global__ __launch_bounds__(256) void transpose_v(const unsigned short* __restrict__ vb16,
                                                   unsigned short* __restrict__ vtb) {
  __shared__ unsigned short tile[32][33];
  int t0 = blockIdx.x * 32, d0 = blockIdx.y * 32, b = blockIdx.z;
  int tx = threadIdx.x & 31, ty = threadIdx.x >> 5;
#pragma unroll
  for (int i = 0; i < 4; ++i) {
    int t = ty + i * 8;
    tile[t][tx] = vb16[((size_t)(b * 2048 + t0 + t)) * 512 + d0 + tx];
  }
  __syncthreads();
#pragma unroll
  for (int i = 0; i < 4; ++i) {
    int d = ty + i * 8;
    int D = d0 + d;
    vtb[((size_t)((b * 4 + (D >> 7)) * 128 + (D & 127))) * 2048 + t0 + tx] = tile[tx][d];
  }
}

// --- softmax + P-stage macro (literal SUB keeps all indexing static) -------
#define SOFTMAX_STAGE(SUB, S0, S1, MM, LL, OA)                                 \
  {                                                                            \
    int q0s = q0w + SUB * 16;                                                  \
    if (k0 + 31 > q0s) {                                                       \
      int kq0 = k0 + g * 4 - (q0s + c);                                        \
      _Pragma("unroll")                                                        \
      for (int r = 0; r < 4; ++r) {                                            \
        if (kq0 + r > 0)      S0[r] = -INFINITY;                               \
        if (kq0 + 16 + r > 0) S1[r] = -INFINITY;                               \
      }                                                                        \
    }                                                                          \
    float mx = fmaxf(fmaxf(fmaxf(S0[0], S0[1]), fmaxf(S0[2], S0[3])),          \
                     fmaxf(fmaxf(S1[0], S1[1]), fmaxf(S1[2], S1[3])));         \
    mx = fmaxf(mx, __shfl_xor(mx, 16));                                        \
    mx = fmaxf(mx, __shfl_xor(mx, 32));                                        \
    if (__any(mx > MM)) {                                                      \
      float mn = fmaxf(MM, mx);                                                \
      float corr = __expf(MM - mn);                                            \
      LL *= corr;                                                              \
      _Pragma("unroll")                                                        \
      for (int r = 0; r < 4; ++r) {                                            \
        float corrT = __shfl(corr, g * 4 + r);                                 \
        _Pragma("unroll")                                                      \
        for (int ch = 0; ch < 8; ++ch) OA[ch][r] *= corrT;                     \
      }                                                                        \
      MM = mn;                                                                 \
    }                                                                          \
    float p00 = __expf(S0[0] - MM), p01 = __expf(S0[1] - MM);                  \
    float p02 = __expf(S0[2] - MM), p03 = __expf(S0[3] - MM);                  \
    float p10 = __expf(S1[0] - MM), p11 = __expf(S1[1] - MM);                  \
    float p12 = __expf(S1[2] - MM), p13 = __expf(S1[3] - MM);                  \
    float rs = ((p00 + p01) + (p02 + p03)) + ((p10 + p11) + (p12 + p13));      \
    rs += __shfl_xor(rs, 16);                                                  \
    rs += __shfl_xor(rs, 32);                                                  \
    LL += rs;                                                                  \
    uint2 u0, u1;                                                              \
    u0.x = pack2bf(p00, p01); u0.y = pack2bf(p02, p03);                        \
    u1.x = pack2bf(p10, p11); u1.y = pack2bf(p12, p13);                        \
    *(uint2*)(&plds[w][SUB][c][g * 4])      = u0;                              \
    *(uint2*)(&plds[w][SUB][c][16 + g * 4]) = u1;                              \
  }

#define EPILOGUE(SUB, LL, OA)                                                  \
  {                                                                            \
    _Pragma("unroll")                                                          \
    for (int r = 0; r < 4; ++r) {                                              \
      float lT = __shfl(LL, g * 4 + r);                                        \
      float inv = 1.f / lT;                                                    \
      int qi = q0w + SUB * 16 + g * 4 + r;                                     \
      unsigned short* orow = attob + ((size_t)(b * 2048 + qi)) * 2048 + h*128; \
      _Pragma("unroll")                                                        \
      for (int ch = 0; ch < 8; ++ch) orow[ch * 16 + c] = f2bf(OA[ch][r]*inv);  \
    }                                                                          \
  }

// --- MFMA flash attention: 2 waves x 32q, DMA-staged K/V -------------------
// Block = 2 waves; wave w covers queries q0w = 64*jj + 32*w .. +31 as two
// 16q subtiles sharing each K/V fragment read. K [32][128] and V^T [128][32]
// double-buffered in LDS via global_load_lds with pre-swizzled source.
__global__ __launch_bounds__(128, 2) void attn_mfma(const unsigned short* __restrict__ qb,
                                                    const unsigned short* __restrict__ kb,
                                                    const unsigned short* __restrict__ vtb,
                                                    unsigned short* __restrict__ attob) {
  __shared__ unsigned short lds_k[2][4096];   // 2 x 8 KB
  __shared__ unsigned short lds_v[2][4096];   // 2 x 8 KB
  __shared__ unsigned short plds[2][2][16][40];

  int tid = threadIdx.x;
  int w = tid >> 6, lane = tid & 63;
  int g = lane >> 4, c = lane & 15;

  int s = blockIdx.x & 31;
  int stream = blockIdx.x >> 5;
  int jj = (s & 1) ? (31 - (s >> 1)) : (s >> 1);  // balanced pairing
  int h = stream & 15, b = stream >> 4;
  int kvh = h >> 2;
  int q0w = 64 * jj + 32 * w;
  int nt_own = (q0w + 47) >> 5;    // same for both subtiles (q0w % 32 == 0)
  int nt_blk = 2 * jj + 2;

  const unsigned short* kbase = kb + (size_t)b * 2048 * 512 + kvh * 128;
  const unsigned short* vtbase = vtb + (size_t)(b * 4 + kvh) * 128 * 2048;

  // Q fragments, both subtiles
  bf16x8 qaA[4], qaB[4];
  {
    const unsigned short* qr0 = qb + ((size_t)(b * 2048 + q0w + c)) * 2048 + h * 128;
    const unsigned short* qr1 = qr0 + (size_t)16 * 2048;
#pragma unroll
    for (int kc = 0; kc < 4; ++kc) {
      qaA[kc] = *(const bf16x8*)(qr0 + kc * 32 + g * 8);
      qaB[kc] = *(const bf16x8*)(qr1 + kc * 32 + g * 8);
    }
  }

  // Pre-swizzled DMA source pointers: linear LDS slot L -> inverse-swizzled
  // global (row, chunk). Wave w stages bytes [w*4096, w*4096+4096) of each tile.
  const unsigned short* srcK[4];
  const unsigned short* srcV[4];
#pragma unroll
  for (int i = 0; i < 4; ++i) {
    int L = w * 4096 + i * 1024 + lane * 16;     // byte offset in 8KB tile
    int rk = L >> 8;                             // K: row = L/256
    int ck = ((L >> 4) & 15) ^ (rk & 7);
    srcK[i] = kbase + (size_t)rk * 512 + ck * 8;
    int rhi = L >> 7;                            // V^T: row*64 with bit6 XOR
    int r0 = ((L >> 6) & 1) ^ ((rhi >> 1) & 1);
    int rv = (rhi << 1) | r0;
    int cv = ((L >> 4) & 3) ^ (rv & 3);
    srcV[i] = vtbase + (size_t)rv * 2048 + cv * 8;
  }

  f32x4 o_accA[8], o_accB[8];
#pragma unroll
  for (int ch = 0; ch < 8; ++ch) {
    o_accA[ch] = (f32x4){0.f, 0.f, 0.f, 0.f};
    o_accB[ch] = (f32x4){0.f, 0.f, 0.f, 0.f};
  }
  float mA = -INFINITY, lA = 0.f, mB = -INFINITY, lB = 0.f;

  // ---- prologue: DMA tile 0 into buf 0 ----
#pragma unroll
  for (int i = 0; i < 4; ++i) {
    __builtin_amdgcn_global_load_lds((const AS1 void*)(srcK[i]),
        (AS3 void*)(&lds_k[0][w * 2048 + i * 512]), 16, 0, 0);
    __builtin_amdgcn_global_load_lds((const AS1 void*)(srcV[i]),
        (AS3 void*)(&lds_v[0][w * 2048 + i * 512]), 16, 0, 0);
  }
  __syncthreads();

  int cur = 0;
  for (int ti = 0; ti < nt_blk; ++ti) {
    int k0 = ti * 32;
    if (ti + 1 < nt_blk) {   // DMA next tile into buf cur^1 (fire-and-forget)
      int nb = cur ^ 1;
      int k1s = (k0 + 32) * 512;   // K source offset (shorts)
      int k1v = k0 + 32;           // V^T source offset (shorts)
#pragma unroll
      for (int i = 0; i < 4; ++i) {
        __builtin_amdgcn_global_load_lds((const AS1 void*)(srcK[i] + k1s),
            (AS3 void*)(&lds_k[nb][w * 2048 + i * 512]), 16, 0, 0);
        __builtin_amdgcn_global_load_lds((const AS1 void*)(srcV[i] + k1v),
            (AS3 void*)(&lds_v[nb][w * 2048 + i * 512]), 16, 0, 0);
      }
    }
    if (ti < nt_own) {
      // ---- swapped QK^T, both subtiles share kf reads ----
      f32x4 sA0 = (f32x4){0.f,0.f,0.f,0.f}, sA1 = (f32x4){0.f,0.f,0.f,0.f};
      f32x4 sB0 = (f32x4){0.f,0.f,0.f,0.f}, sB1 = (f32x4){0.f,0.f,0.f,0.f};
      __builtin_amdgcn_s_setprio(1);
#pragma unroll
      for (int kc = 0; kc < 4; ++kc) {
        bf16x8 kf0 = *(const bf16x8*)&lds_k[cur][swzK(c, kc * 4 + g)];
        bf16x8 kf1 = *(const bf16x8*)&lds_k[cur][swzK(16 + c, kc * 4 + g)];
        sA0 = __builtin_amdgcn_mfma_f32_16x16x32_bf16(kf0, qaA[kc], sA0, 0, 0, 0);
        sA1 = __builtin_amdgcn_mfma_f32_16x16x32_bf16(kf1, qaA[kc], sA1, 0, 0, 0);
        sB0 = __builtin_amdgcn_mfma_f32_16x16x32_bf16(kf0, qaB[kc], sB0, 0, 0, 0);
        sB1 = __builtin_amdgcn_mfma_f32_16x16x32_bf16(kf1, qaB[kc], sB1, 0, 0, 0);
      }
      __builtin_amdgcn_s_setprio(0);
      // ---- softmax + P-stage per subtile (independent chains) ----
      SOFTMAX_STAGE(0, sA0, sA1, mA, lA, o_accA);
      SOFTMAX_STAGE(1, sB0, sB1, mB, lB, o_accB);
      // ---- PV, both subtiles share vf reads ----
      bf16x8 paA = *(const bf16x8*)(&plds[w][0][c][g * 8]);
      bf16x8 paB = *(const bf16x8*)(&plds[w][1][c][g * 8]);
      __builtin_amdgcn_s_setprio(1);
#pragma unroll
      for (int ch = 0; ch < 8; ++ch) {
        bf16x8 vf = *(const bf16x8*)&lds_v[cur][swzV(ch * 16 + c, g)];
        o_accA[ch] = __builtin_amdgcn_mfma_f32_16x16x32_bf16(paA, vf, o_accA[ch], 0, 0, 0);
        o_accB[ch] = __builtin_amdgcn_mfma_f32_16x16x32_bf16(paB, vf, o_accB[ch], 0, 0, 0);
      }
      __builtin_amdgcn_s_setprio(0);
    }
    __syncthreads();   // drains DMA vmcnt + all lds reads; buffers flip safely
    cur ^= 1;
  }
  // ---- epilogue ----
  EPILOGUE(0, lA, o_accA);
  EPILOGUE(1, lB, o_accB);
}

// ---------------------------------------------------------------------------
extern "C" void kernel_launch(void* const* d_in, const int* in_sizes, int n_in,
                              void* d_out, int out_size, void* d_ws, size_t ws_size,
                              hipStream_t stream) {
  const float* x   = (const float*)d_in[0];
  const float* wq  = (const float*)d_in[1];
  const float* wkv = (const float*)d_in[2];
  const float* wk  = (const float*)d_in[3];
  const float* wv  = (const float*)d_in[4];
  const float* wo  = (const float*)d_in[5];
  float* out = (float*)d_out;
  float* ws  = (float*)d_ws;

  const int B = 2, T = 2048, H = 2048, NH = 16, NKV = 4, LAT = 256, KVD = 512;
  const int BT = B * T;  // 4096

  size_t off = 0;
  unsigned short* xb   = (unsigned short*)(ws + off); off += (size_t)BT * H / 2;
  unsigned short* wqb  = (unsigned short*)(ws + off); off += (size_t)H * H / 2;
  unsigned short* wkvb = (unsigned short*)(ws + off); off += (size_t)LAT * H / 2;
  unsigned short* wkb  = (unsigned short*)(ws + off); off += (size_t)KVD * LAT / 2;
  unsigned short* wvb  = (unsigned short*)(ws + off); off += (size_t)KVD * LAT / 2;
  unsigned short* wob  = (unsigned short*)(ws + off); off += (size_t)H * H / 2;
  unsigned short* qb   = (unsigned short*)(ws + off); off += (size_t)BT * H / 2;
  unsigned short* kvlb = (unsigned short*)(ws + off); off += (size_t)BT * LAT / 2;
  unsigned short* kb   = (unsigned short*)(ws + off); off += (size_t)BT * KVD / 2;
  unsigned short* vb16 = (unsigned short*)(ws + off); off += (size_t)BT * KVD / 2;
  unsigned short* vtb  = (unsigned short*)(ws + off); off += (size_t)BT * KVD / 2;
  unsigned short* attob= (unsigned short*)(ws + off); off += (size_t)BT * H / 2;
  float* cost = ws + off; off += (size_t)T * 64;
  float* sint = ws + off; off += (size_t)T * 64;

  const float scale = 0.088388347648318447f;  // 1/sqrt(128)

  rope_table<<<(T * 64 + 255) / 256, 256, 0, stream>>>(cost, sint, T);

  conv_bf16<<<(BT * H / 4) / 256, 256, 0, stream>>>(x, xb, BT * H);
  conv_bf16<<<(H * H / 4) / 256, 256, 0, stream>>>(wq, wqb, H * H);
  conv_bf16<<<(LAT * H / 4) / 256, 256, 0, stream>>>(wkv, wkvb, LAT * H);
  conv_bf16<<<(KVD * LAT / 4) / 256, 256, 0, stream>>>(wk, wkb, KVD * LAT);
  conv_bf16<<<(KVD * LAT / 4) / 256, 256, 0, stream>>>(wv, wvb, KVD * LAT);
  conv_bf16<<<(H * H / 4) / 256, 256, 0, stream>>>(wo, wob, H * H);

  gemm_mfma<true><<<dim3(H / 128, BT / 128), 256, 0, stream>>>(xb, wqb, qb, BT, H, H);
  gemm_mfma<true><<<dim3(LAT / 128, BT / 128), 256, 0, stream>>>(xb, wkvb, kvlb, BT, LAT, H);
  gemm_mfma<true><<<dim3(KVD / 128, BT / 128), 256, 0, stream>>>(kvlb, wkb, kb, BT, KVD, LAT);
  gemm_mfma<true><<<dim3(KVD / 128, BT / 128), 256, 0, stream>>>(kvlb, wvb, vb16, BT, KVD, LAT);

  rope_ip_bf16<<<(BT * NH * 64) / 256, 256, 0, stream>>>(qb, NH, T, cost, sint, scale);
  rope_ip_bf16<<<(BT * NKV * 64) / 256, 256, 0, stream>>>(kb, NKV, T, cost, sint, 1.0f);

  transpose_v<<<dim3(T / 32, KVD / 32, B), 256, 0, stream>>>(vb16, vtb);

  // 1024 blocks = 32 balanced q-groups x 32 streams, 2 waves each
  attn_mfma<<<1024, 128, 0, stream>>>(qb, kb, vtb, attob);

  gemm_mfma<false><<<dim3(H / 128, BT / 128), 256, 0, stream>>>(attob, wob, out, BT, H, H);
}